// Round 6
// baseline (374.049 us; speedup 1.0000x reference)
//
#include <hip/hip_runtime.h>
#include <math.h>

typedef _Float16 f16_t;
typedef _Float16 f16x8 __attribute__((ext_vector_type(8)));
typedef _Float16 f16x4 __attribute__((ext_vector_type(4)));
typedef _Float16 f16x2 __attribute__((ext_vector_type(2)));
typedef __fp16 h16x2 __attribute__((ext_vector_type(2)));
typedef float f32x4 __attribute__((ext_vector_type(4)));

#define LDS_BYTES 70656

// fp32 -> fp16 weights into d_ws, FRAGMENT-LINEAR (same as round 5, verified):
// for global chunk ck (0..11: W1 ck0..3, W2 ck0..7) and feat-16-group f (0..15),
// the 1 KB block at (ck*16+f)*1024 bytes holds the MFMA A-fragment in exact lane
// order: lane l = q*16+c holds feats f*16+c, k = ck*32 + q*8 .. +7.
__global__ void wconv(const float* __restrict__ W1, const float* __restrict__ W2,
                      f16_t* __restrict__ o) {
  int i = blockIdx.x * 256 + threadIdx.x;  // 0..65535
  if (i < 32768) {
    int n = i >> 7, k = i & 127;
    int ck = k >> 5, q = (k >> 3) & 3, j = k & 7;
    int f = n >> 4, c = n & 15;
    o[ck * 8192 + f * 512 + (q * 16 + c) * 8 + j] = (f16_t)W1[i];
  }
  {
    int n = i >> 8, k = i & 255;
    int ck = k >> 5, q = (k >> 3) & 3, j = k & 7;
    int f = n >> 4, c = n & 15;
    o[32768 + ck * 8192 + f * 512 + (q * 16 + c) * 8 + j] = (f16_t)W2[i];
  }
}

__device__ __forceinline__ f16x2 pk2(float a, float b) {
  union { h16x2 h; f16x2 f; } u;
  u.h = __builtin_amdgcn_cvt_pkrtz(a, b);
  return u.f;
}

#define COMP(v, r) ((r) == 0 ? (v).x : (r) == 1 ? (v).y : (r) == 2 ? (v).z : (v).w)

// lgkm-only barrier: orders LDS data; weight loads (VMEM, same-thread data deps
// only) stay in flight across every barrier.
#define LGKMBAR() do { \
    asm volatile("s_waitcnt lgkmcnt(0)" ::: "memory"); \
    __builtin_amdgcn_s_barrier(); } while (0)

#define MFMA16(a, b, d) d = __builtin_amdgcn_mfma_f32_16x16x32_f16(a, b, d, 0, 0, 0)

// Transposed fused MLP: D[feat][edge] = W @ x^T. Tile = 128 edges, 512 threads,
// 8 waves as 4 feat-rows (64 feats) x 2 edge-cols (64 edges). acc[4][4] = 64
// regs/wave (16 MFMA per k-step per wave -> each af fragment feeds 16 MFMAs).
// ROUND-6: the occupancy-invariance of r0(16w/CU)=r4(32w/CU)=~254us says the
// bound is per-CU LDS/issue WORK VOLUME, not latency hiding. So: (a) weights
// direct-to-VGPR (r5's layout) -- no LDS ring, no staging, ZERO barriers in
// both GEMM k-loops; af reloaded in-place per k-step (msf-interleaved with the
// MFMA clusters so L2 latency hides under compute); (b) 2x edge tile with
// acc[4][4] cuts per-edge ds_reads 12->3, barriers/edge 5x, loop VALU /2,
// and per-edge weight L2 traffic 2x vs r5. LDS = x1 64K + stats = 70656 B
// -> 2 blocks/CU (two barrier domains). Target VGPR <=128 (4 waves/SIMD,
// 16 waves/CU = r0's proven-sufficient occupancy). Plain launch_bounds (r3).
__global__ __launch_bounds__(512) void fused_mlp(
    const float* __restrict__ h,
    const int* __restrict__ src,
    const int* __restrict__ dst,
    const f16_t* __restrict__ wks,
    const float* __restrict__ b1, const float* __restrict__ g1, const float* __restrict__ be1,
    const float* __restrict__ b2, const float* __restrict__ g2, const float* __restrict__ be2,
    const float* __restrict__ w3, const float* __restrict__ b3,
    float* __restrict__ out, int E, int nrows) {
  extern __shared__ __attribute__((aligned(16))) char smem[];
  f16_t* xbuf = (f16_t*)smem;               // x0 [128][128] (32K); later x1 [128][256] (64K)
  float* ssum = (float*)(smem + 65536);     // [4 wf][128 e]
  float* ssq  = (float*)(smem + 67584);     // [4 wf][128 e]
  float* smean = (float*)(smem + 69632);    // [128]
  float* srstd = (float*)(smem + 70144);    // [128]

  const int t = threadIdx.x;
  const int ebase = blockIdx.x * 128;

  const int lane = t & 63;
  const int wave = t >> 6;   // 0..7
  const int wf = wave >> 1;  // 0..3: 64 feats each
  const int we = wave & 1;   // 0..1: 64 edges each
  const int c = lane & 15;
  const int q = lane >> 4;
  const int featBase = wf * 64;
  const int eb = we * 64 + c;              // edge n: eb + n*16

  const f16_t* wp = wks + lane * 8;        // + (ck*16 + wf*4 + msf)*512

  // Weight prologue: GEMM1 chunk 0 fragments (in flight through the gather).
  f16x8 af[4];
#pragma unroll
  for (int m2 = 0; m2 < 4; ++m2)
    af[m2] = *(const f16x8*)(wp + (wf * 4 + m2) * 512);

  // ---------- gather: x0[m][k] = h[src][k]*h[dst][k], fp16, swizzled stride-128 ----
  // 4 threads per edge, 32 floats each.
  {
    const int m = t >> 2;   // edge 0..127
    const int j2 = t & 3;   // 32-float slice
    const int e = ebase + m;
    f16_t* xrow = xbuf + m * 128;
    if (e < E) {
      int si = src[e], di = dst[e];
      si = ((unsigned)si < (unsigned)nrows) ? si : 0;
      di = ((unsigned)di < (unsigned)nrows) ? di : 0;
      const float* hs = h + (long long)si * 128 + j2 * 32;
      const float* hd = h + (long long)di * 128 + j2 * 32;
#pragma unroll
      for (int u = 0; u < 4; ++u) {
        const float4 a0 = *(const float4*)(hs + u * 8);
        const float4 a1 = *(const float4*)(hs + u * 8 + 4);
        const float4 c0 = *(const float4*)(hd + u * 8);
        const float4 c1 = *(const float4*)(hd + u * 8 + 4);
        union { f16x8 v8; f16x2 v2[4]; } u0;
        u0.v2[0] = pk2(a0.x * c0.x, a0.y * c0.y);
        u0.v2[1] = pk2(a0.z * c0.z, a0.w * c0.w);
        u0.v2[2] = pk2(a1.x * c1.x, a1.y * c1.y);
        u0.v2[3] = pk2(a1.z * c1.z, a1.w * c1.w);
        const int gw = ((j2 * 4 + u) ^ (m & 15)) & 15;
        *(f16x8*)(xrow + gw * 8) = u0.v8;
      }
    } else {
      f16x8 z = {};
#pragma unroll
      for (int u = 0; u < 4; ++u) {
        const int gw = ((j2 * 4 + u) ^ (m & 15)) & 15;
        *(f16x8*)(xrow + gw * 8) = z;
      }
    }
  }
  LGKMBAR();  // b1: x0 visible (weight loads still in flight)

  // ---------- GEMM1: K=128, chunks 0..3, ZERO barriers ----------
  f32x4 acc[4][4];
#pragma unroll
  for (int m2 = 0; m2 < 4; ++m2)
#pragma unroll
    for (int n = 0; n < 4; ++n) acc[m2][n] = (f32x4){0.f, 0.f, 0.f, 0.f};

#pragma unroll
  for (int j = 0; j < 4; ++j) {
    const int gp = ((j * 4 + q) ^ c) & 15;
    const f16_t* xr = xbuf + eb * 128 + gp * 8;
    const f16x8 bf0 = *(const f16x8*)(xr);
    const f16x8 bf1 = *(const f16x8*)(xr + 16 * 128);
    const f16x8 bf2 = *(const f16x8*)(xr + 32 * 128);
    const f16x8 bf3 = *(const f16x8*)(xr + 48 * 128);
#pragma unroll
    for (int m2 = 0; m2 < 4; ++m2) {
      const f16x8 a = af[m2];
      // reload this slot for the next chunk (j=3 loads GEMM2's chunk 4) --
      // the load's L2 latency hides under the 16 MFMAs below / next iters.
      af[m2] = *(const f16x8*)(wp + ((j + 1) * 16 + wf * 4 + m2) * 512);
      MFMA16(a, bf0, acc[m2][0]);
      MFMA16(a, bf1, acc[m2][1]);
      MFMA16(a, bf2, acc[m2][2]);
      MFMA16(a, bf3, acc[m2][3]);
    }
  }

  // ---------- LN1 stats ----------
  {
    float s[4] = {0.f, 0.f, 0.f, 0.f}, sq[4] = {0.f, 0.f, 0.f, 0.f};
#pragma unroll
    for (int m2 = 0; m2 < 4; ++m2) {
      const float4 bv = *(const float4*)(b1 + featBase + m2 * 16 + q * 4);
#pragma unroll
      for (int r = 0; r < 4; ++r) {
        const float b = COMP(bv, r);
#pragma unroll
        for (int n = 0; n < 4; ++n) {
          float v = acc[m2][n][r] + b;
          acc[m2][n][r] = v;
          s[n] += v; sq[n] += v * v;
        }
      }
    }
#pragma unroll
    for (int n = 0; n < 4; ++n) {
      s[n] += __shfl_xor(s[n], 16, 64); s[n] += __shfl_xor(s[n], 32, 64);
      sq[n] += __shfl_xor(sq[n], 16, 64); sq[n] += __shfl_xor(sq[n], 32, 64);
    }
    if (q == 0) {
#pragma unroll
      for (int n = 0; n < 4; ++n) {
        ssum[wf * 128 + eb + n * 16] = s[n];
        ssq[wf * 128 + eb + n * 16] = sq[n];
      }
    }
  }
  LGKMBAR();  // b2: partials visible; all x0 reads drained

  if (t < 128) {
    float s = ssum[t] + ssum[128 + t] + ssum[256 + t] + ssum[384 + t];
    float sq = ssq[t] + ssq[128 + t] + ssq[256 + t] + ssq[384 + t];
    float mu = s * (1.f / 256.f);
    float var = sq * (1.f / 256.f) - mu * mu;
    smean[t] = mu;
    srstd[t] = rsqrtf(var + 1e-5f);
  }
  LGKMBAR();  // b3: mean/rstd ready

  // ---------- LN1 normalize + ReLU -> x1 [128][256] (overwrites x0) ----------
  {
    float rs[4], nmr[4];
#pragma unroll
    for (int n = 0; n < 4; ++n) {
      rs[n] = srstd[eb + n * 16];
      nmr[n] = -smean[eb + n * 16] * rs[n];
    }
    const int j0 = (q & 1) * 4;
#pragma unroll
    for (int m2 = 0; m2 < 4; ++m2) {
      const float4 gv = *(const float4*)(g1 + featBase + m2 * 16 + q * 4);
      const float4 bev = *(const float4*)(be1 + featBase + m2 * 16 + q * 4);
      const int g8 = wf * 8 + m2 * 2 + (q >> 1);   // feat 8-f16-group 0..31
      const int gpw = (g8 & 16) | ((g8 ^ c) & 15);
#pragma unroll
      for (int n = 0; n < 4; ++n) {
        float v0 = fmaxf(fmaf(fmaf(acc[m2][n][0], rs[n], nmr[n]), gv.x, bev.x), 0.f);
        float v1 = fmaxf(fmaf(fmaf(acc[m2][n][1], rs[n], nmr[n]), gv.y, bev.y), 0.f);
        float v2 = fmaxf(fmaf(fmaf(acc[m2][n][2], rs[n], nmr[n]), gv.z, bev.z), 0.f);
        float v3 = fmaxf(fmaf(fmaf(acc[m2][n][3], rs[n], nmr[n]), gv.w, bev.w), 0.f);
        union { f16x4 v4; f16x2 v2[2]; } hh;
        hh.v2[0] = pk2(v0, v1); hh.v2[1] = pk2(v2, v3);
        *(f16x4*)(xbuf + (eb + n * 16) * 256 + gpw * 8 + j0) = hh.v4;
      }
    }
  }
  LGKMBAR();  // b4: x1 visible

  // ---------- GEMM2: K=256, chunks 4..11, ZERO barriers ----------
  f32x4 acc2[4][4];
#pragma unroll
  for (int m2 = 0; m2 < 4; ++m2)
#pragma unroll
    for (int n = 0; n < 4; ++n) acc2[m2][n] = (f32x4){0.f, 0.f, 0.f, 0.f};

#pragma unroll
  for (int j = 0; j < 8; ++j) {   // global chunk 4+j
    const int g = j * 4 + q;      // 0..31
    const int gp = (g & 16) | ((g ^ c) & 15);
    const f16_t* xr = xbuf + eb * 256 + gp * 8;
    const f16x8 bf0 = *(const f16x8*)(xr);
    const f16x8 bf1 = *(const f16x8*)(xr + 16 * 256);
    const f16x8 bf2 = *(const f16x8*)(xr + 32 * 256);
    const f16x8 bf3 = *(const f16x8*)(xr + 48 * 256);
#pragma unroll
    for (int m2 = 0; m2 < 4; ++m2) {
      const f16x8 a = af[m2];
      if (j < 7)
        af[m2] = *(const f16x8*)(wp + ((5 + j) * 16 + wf * 4 + m2) * 512);
      MFMA16(a, bf0, acc2[m2][0]);
      MFMA16(a, bf1, acc2[m2][1]);
      MFMA16(a, bf2, acc2[m2][2]);
      MFMA16(a, bf3, acc2[m2][3]);
    }
  }

  // ---------- LN2 stats ----------
  {
    float s[4] = {0.f, 0.f, 0.f, 0.f}, sq[4] = {0.f, 0.f, 0.f, 0.f};
#pragma unroll
    for (int m2 = 0; m2 < 4; ++m2) {
      const float4 bv = *(const float4*)(b2 + featBase + m2 * 16 + q * 4);
#pragma unroll
      for (int r = 0; r < 4; ++r) {
        const float b = COMP(bv, r);
#pragma unroll
        for (int n = 0; n < 4; ++n) {
          float v = acc2[m2][n][r] + b;
          acc2[m2][n][r] = v;
          s[n] += v; sq[n] += v * v;
        }
      }
    }
#pragma unroll
    for (int n = 0; n < 4; ++n) {
      s[n] += __shfl_xor(s[n], 16, 64); s[n] += __shfl_xor(s[n], 32, 64);
      sq[n] += __shfl_xor(sq[n], 16, 64); sq[n] += __shfl_xor(sq[n], 32, 64);
    }
    if (q == 0) {
#pragma unroll
      for (int n = 0; n < 4; ++n) {
        ssum[wf * 128 + eb + n * 16] = s[n];
        ssq[wf * 128 + eb + n * 16] = sq[n];
      }
    }
  }
  LGKMBAR();  // b5

  if (t < 128) {
    float s = ssum[t] + ssum[128 + t] + ssum[256 + t] + ssum[384 + t];
    float sq = ssq[t] + ssq[128 + t] + ssq[256 + t] + ssq[384 + t];
    float mu = s * (1.f / 256.f);
    float var = sq * (1.f / 256.f) - mu * mu;
    smean[t] = mu;
    srstd[t] = rsqrtf(var + 1e-5f);
  }
  LGKMBAR();  // b6

  // ---------- LN2 normalize + ReLU + dot(W3) + sigmoid ----------
  {
    float rs[4], nmr[4], p[4] = {0.f, 0.f, 0.f, 0.f};
#pragma unroll
    for (int n = 0; n < 4; ++n) {
      rs[n] = srstd[eb + n * 16];
      nmr[n] = -smean[eb + n * 16] * rs[n];
    }
#pragma unroll
    for (int m2 = 0; m2 < 4; ++m2) {
      const float4 gv = *(const float4*)(g2 + featBase + m2 * 16 + q * 4);
      const float4 bev = *(const float4*)(be2 + featBase + m2 * 16 + q * 4);
      const float4 wv = *(const float4*)(w3 + featBase + m2 * 16 + q * 4);
#pragma unroll
      for (int r = 0; r < 4; ++r) {
        const float gr = COMP(gv, r), ber = COMP(bev, r), wr = COMP(wv, r);
#pragma unroll
        for (int n = 0; n < 4; ++n) {
          float v = fmaxf(fmaf(fmaf(acc2[m2][n][r], rs[n], nmr[n]), gr, ber), 0.f);
          p[n] = fmaf(v, wr, p[n]);
        }
      }
    }
#pragma unroll
    for (int n = 0; n < 4; ++n) {
      p[n] += __shfl_xor(p[n], 16, 64); p[n] += __shfl_xor(p[n], 32, 64);
    }
    if (q == 0) {
#pragma unroll
      for (int n = 0; n < 4; ++n)
        ssum[wf * 128 + eb + n * 16] = p[n];   // ssum dead after b6 reduce
    }
  }
  LGKMBAR();  // b7
  if (t < 128) {
    int e = ebase + t;
    if (e < E) {
      float sres = ssum[t] + ssum[128 + t] + ssum[256 + t] + ssum[384 + t] + b3[0];
      out[e] = 1.f / (1.f + __expf(-sres));
    }
  }
}

extern "C" void kernel_launch(void* const* d_in, const int* in_sizes, int n_in,
                              void* d_out, int out_size, void* d_ws, size_t ws_size,
                              hipStream_t stream) {
  const float* h = (const float*)d_in[0];
  const int* src = (const int*)d_in[1];
  const int* dst = (const int*)d_in[2];
  const float* W1 = (const float*)d_in[3];
  const float* b1 = (const float*)d_in[4];
  const float* g1 = (const float*)d_in[5];
  const float* be1 = (const float*)d_in[6];
  const float* W2 = (const float*)d_in[7];
  const float* b2 = (const float*)d_in[8];
  const float* g2 = (const float*)d_in[9];
  const float* be2 = (const float*)d_in[10];
  const float* W3 = (const float*)d_in[11];
  const float* b3 = (const float*)d_in[12];
  float* out = (float*)d_out;
  const int E = in_sizes[1];
  const int nrows = in_sizes[0] / 128;
  f16_t* wks = (f16_t*)d_ws;  // 98304 f16 = 196608 bytes

  wconv<<<256, 256, 0, stream>>>(W1, W2, wks);
  (void)hipFuncSetAttribute((const void*)fused_mlp,
                            hipFuncAttributeMaxDynamicSharedMemorySize, LDS_BYTES);
  const int tiles = (E + 127) / 128;
  fused_mlp<<<tiles, 512, LDS_BYTES, stream>>>(h, src, dst, wks, b1, g1, be1,
                                               b2, g2, be2, W3, b3, out, E, nrows);
}

// Round 7
// 277.767 us; speedup vs baseline: 1.3466x; 1.3466x over previous
//
#include <hip/hip_runtime.h>
#include <math.h>

typedef _Float16 f16_t;
typedef _Float16 f16x8 __attribute__((ext_vector_type(8)));
typedef _Float16 f16x4 __attribute__((ext_vector_type(4)));
typedef _Float16 f16x2 __attribute__((ext_vector_type(2)));
typedef __fp16 h16x2 __attribute__((ext_vector_type(2)));
typedef float f32x4 __attribute__((ext_vector_type(4)));

#define LDS_BYTES 37376

// fp32 -> fp16 weights into d_ws, FRAGMENT-LINEAR (verified r5/r6): for global
// chunk ck (0..11: W1 ck0..3, W2 ck0..7) and feat-16-group f (0..15), the 1 KB
// block at (ck*16+f)*1024 bytes holds the MFMA A-fragment in exact lane order:
// lane l = q*16+c holds feats f*16+c, k = ck*32 + q*8 .. +7.
__global__ void wconv(const float* __restrict__ W1, const float* __restrict__ W2,
                      f16_t* __restrict__ o) {
  int i = blockIdx.x * 256 + threadIdx.x;  // 0..65535
  if (i < 32768) {
    int n = i >> 7, k = i & 127;
    int ck = k >> 5, q = (k >> 3) & 3, j = k & 7;
    int f = n >> 4, c = n & 15;
    o[ck * 8192 + f * 512 + (q * 16 + c) * 8 + j] = (f16_t)W1[i];
  }
  {
    int n = i >> 8, k = i & 255;
    int ck = k >> 5, q = (k >> 3) & 3, j = k & 7;
    int f = n >> 4, c = n & 15;
    o[32768 + ck * 8192 + f * 512 + (q * 16 + c) * 8 + j] = (f16_t)W2[i];
  }
}

__device__ __forceinline__ f16x2 pk2(float a, float b) {
  union { h16x2 h; f16x2 f; } u;
  u.h = __builtin_amdgcn_cvt_pkrtz(a, b);
  return u.f;
}

#define COMP(v, r) ((r) == 0 ? (v).x : (r) == 1 ? (v).y : (r) == 2 ? (v).z : (v).w)

// lgkm-only barrier: orders LDS data; weight loads (VMEM, same-thread data deps
// only) stay in flight across every barrier.
#define LGKMBAR() do { \
    asm volatile("s_waitcnt lgkmcnt(0)" ::: "memory"); \
    __builtin_amdgcn_s_barrier(); } while (0)

#define MFMA16(a, b, d) d = __builtin_amdgcn_mfma_f32_16x16x32_f16(a, b, d, 0, 0, 0)

// Transposed fused MLP: D[feat][edge] = W @ x^T. Tile = 64 edges, 512 threads,
// 8 waves; EACH WAVE = one 32-feat row x ALL 64 edges (acc[2][4] = 32 regs,
// reused across both GEMMs).
// ROUND-7 SYNTHESIS of r0..r6 evidence: the shared per-CU LDS pipe at ~70%
// (af reads 4.6K + staging 1.5K + bf/x/shfl ~4.6K cyc/tile of a 15.6K budget)
// is the floor -- occupancy-invariant (r0=r4), staging-schedule-invariant (r2).
// Fix: weights direct-to-VGPR (r5 layout) with the geometry r5/r6 lacked:
//  - one wave per fragment -> weight L2 traffic 192KB/tile (r5 had 2x);
//  - 8 MFMAs per 2-fragment set (r5 had 4) -> latency covered;
//  - prefetch depth 2, stream continuous across LN1 (ck4,5 load in GEMM1 tail);
//  - acc reuse keeps regs ~<=120 -> 4 waves/SIMD, 2 blocks/CU, two domains.
// LDS pipe drops to ~5.5K cyc/tile (bf reads + x writes + shfl only); zero
// barriers inside both k-loops; 7 lgkm-only barriers total.
__global__ __launch_bounds__(512) void fused_mlp(
    const float* __restrict__ h,
    const int* __restrict__ src,
    const int* __restrict__ dst,
    const f16_t* __restrict__ wks,
    const float* __restrict__ b1, const float* __restrict__ g1, const float* __restrict__ be1,
    const float* __restrict__ b2, const float* __restrict__ g2, const float* __restrict__ be2,
    const float* __restrict__ w3, const float* __restrict__ b3,
    float* __restrict__ out, int E, int nrows) {
  extern __shared__ __attribute__((aligned(16))) char smem[];
  f16_t* xbuf = (f16_t*)smem;               // x0 [64][128] (16K); later x1 [64][256] (32K)
  float* ssum = (float*)(smem + 32768);     // [8 wf][64 e]
  float* ssq  = (float*)(smem + 34816);     // [8 wf][64 e]
  float* smean = (float*)(smem + 36864);    // [64]
  float* srstd = (float*)(smem + 37120);    // [64]

  const int t = threadIdx.x;
  const int ebase = blockIdx.x * 64;

  const int lane = t & 63;
  const int wf = t >> 6;     // wave 0..7 = feat-row: feats wf*32 .. wf*32+31
  const int c = lane & 15;
  const int q = lane >> 4;
  const int featBase = wf * 32;

  const f16_t* wp = wks + lane * 8;  // + (ck*16 + wf*2 + m2)*512

  // Weight prologue: chunks 0,1 into the 2-deep register ring (in flight
  // through the gather; each fragment owned by exactly one wave).
  f16x8 afb[2][2];
#pragma unroll
  for (int m2 = 0; m2 < 2; ++m2) {
    afb[0][m2] = *(const f16x8*)(wp + (0 * 16 + wf * 2 + m2) * 512);
    afb[1][m2] = *(const f16x8*)(wp + (1 * 16 + wf * 2 + m2) * 512);
  }

  // ---------- gather: x0[m][k] = h[src][k]*h[dst][k], fp16, swizzled stride-128 ----
  // 8 threads per edge, 16 floats each (r2's verified gather).
  {
    const int m = t >> 3;   // edge 0..63
    const int j = t & 7;    // 16-float slice
    const int e = ebase + m;
    f16_t* xrow = xbuf + m * 128;
    const int g0 = ((j * 2) ^ m) & 15;
    const int g1i = ((j * 2 + 1) ^ m) & 15;
    if (e < E) {
      int si = src[e], di = dst[e];
      si = ((unsigned)si < (unsigned)nrows) ? si : 0;
      di = ((unsigned)di < (unsigned)nrows) ? di : 0;
      const float* hs = h + (long long)si * 128 + j * 16;
      const float* hd = h + (long long)di * 128 + j * 16;
      const float4 a0 = *(const float4*)(hs);
      const float4 a1 = *(const float4*)(hs + 4);
      const float4 a2 = *(const float4*)(hs + 8);
      const float4 a3 = *(const float4*)(hs + 12);
      const float4 c0 = *(const float4*)(hd);
      const float4 c1 = *(const float4*)(hd + 4);
      const float4 c2 = *(const float4*)(hd + 8);
      const float4 c3 = *(const float4*)(hd + 12);
      union { f16x8 v8; f16x2 v2[4]; } u0, u1;
      u0.v2[0] = pk2(a0.x * c0.x, a0.y * c0.y);
      u0.v2[1] = pk2(a0.z * c0.z, a0.w * c0.w);
      u0.v2[2] = pk2(a1.x * c1.x, a1.y * c1.y);
      u0.v2[3] = pk2(a1.z * c1.z, a1.w * c1.w);
      u1.v2[0] = pk2(a2.x * c2.x, a2.y * c2.y);
      u1.v2[1] = pk2(a2.z * c2.z, a2.w * c2.w);
      u1.v2[2] = pk2(a3.x * c3.x, a3.y * c3.y);
      u1.v2[3] = pk2(a3.z * c3.z, a3.w * c3.w);
      *(f16x8*)(xrow + g0 * 8) = u0.v8;
      *(f16x8*)(xrow + g1i * 8) = u1.v8;
    } else {
      f16x8 z = {};
      *(f16x8*)(xrow + g0 * 8) = z;
      *(f16x8*)(xrow + g1i * 8) = z;
    }
  }
  LGKMBAR();  // b1: x0 visible (weight loads still in flight)

  // ---------- GEMM1: K=128, chunks 0..3, ZERO barriers ----------
  f32x4 acc[2][4];
#pragma unroll
  for (int m2 = 0; m2 < 2; ++m2)
#pragma unroll
    for (int n = 0; n < 4; ++n) acc[m2][n] = (f32x4){0.f, 0.f, 0.f, 0.f};

#pragma unroll
  for (int j = 0; j < 4; ++j) {
    const int gp = ((j * 4 + q) ^ c) & 15;
    const f16_t* xr = xbuf + c * 128 + gp * 8;
    const f16x8 bf0 = *(const f16x8*)(xr);
    const f16x8 bf1 = *(const f16x8*)(xr + 16 * 128);
    const f16x8 bf2 = *(const f16x8*)(xr + 32 * 128);
    const f16x8 bf3 = *(const f16x8*)(xr + 48 * 128);
    const f16x8 a0 = afb[j & 1][0];
    const f16x8 a1 = afb[j & 1][1];
    // Reload this ring slot with chunk j+2 (j=2 -> ck4, j=3 -> ck5: GEMM2's
    // first chunks ride across the whole LN1 phase).
    afb[j & 1][0] = *(const f16x8*)(wp + ((j + 2) * 16 + wf * 2 + 0) * 512);
    afb[j & 1][1] = *(const f16x8*)(wp + ((j + 2) * 16 + wf * 2 + 1) * 512);
    MFMA16(a0, bf0, acc[0][0]);
    MFMA16(a0, bf1, acc[0][1]);
    MFMA16(a0, bf2, acc[0][2]);
    MFMA16(a0, bf3, acc[0][3]);
    MFMA16(a1, bf0, acc[1][0]);
    MFMA16(a1, bf1, acc[1][1]);
    MFMA16(a1, bf2, acc[1][2]);
    MFMA16(a1, bf3, acc[1][3]);
  }

  // ---------- LN1 stats ----------
  {
    float s[4] = {0.f, 0.f, 0.f, 0.f}, sq[4] = {0.f, 0.f, 0.f, 0.f};
#pragma unroll
    for (int m2 = 0; m2 < 2; ++m2) {
      const float4 bv = *(const float4*)(b1 + featBase + m2 * 16 + q * 4);
#pragma unroll
      for (int r = 0; r < 4; ++r) {
        const float b = COMP(bv, r);
#pragma unroll
        for (int n = 0; n < 4; ++n) {
          float v = acc[m2][n][r] + b;
          acc[m2][n][r] = v;
          s[n] += v; sq[n] += v * v;
        }
      }
    }
#pragma unroll
    for (int n = 0; n < 4; ++n) {
      s[n] += __shfl_xor(s[n], 16, 64); s[n] += __shfl_xor(s[n], 32, 64);
      sq[n] += __shfl_xor(sq[n], 16, 64); sq[n] += __shfl_xor(sq[n], 32, 64);
    }
    if (q == 0) {
#pragma unroll
      for (int n = 0; n < 4; ++n) {
        ssum[wf * 64 + n * 16 + c] = s[n];
        ssq[wf * 64 + n * 16 + c] = sq[n];
      }
    }
  }
  LGKMBAR();  // b2: partials visible; all x0 reads drained

  if (t < 64) {
    float s = 0.f, sq = 0.f;
#pragma unroll
    for (int w = 0; w < 8; ++w) { s += ssum[w * 64 + t]; sq += ssq[w * 64 + t]; }
    float mu = s * (1.f / 256.f);
    float var = sq * (1.f / 256.f) - mu * mu;
    smean[t] = mu;
    srstd[t] = rsqrtf(var + 1e-5f);
  }
  LGKMBAR();  // b3: mean/rstd ready

  // ---------- LN1 normalize + ReLU -> x1 [64][256] (overwrites x0) ----------
  {
    float rs[4], nmr[4];
#pragma unroll
    for (int n = 0; n < 4; ++n) {
      rs[n] = srstd[n * 16 + c];
      nmr[n] = -smean[n * 16 + c] * rs[n];
    }
    const int j0 = (q & 1) * 4;
#pragma unroll
    for (int m2 = 0; m2 < 2; ++m2) {
      const float4 gv = *(const float4*)(g1 + featBase + m2 * 16 + q * 4);
      const float4 bev = *(const float4*)(be1 + featBase + m2 * 16 + q * 4);
      const int g8 = wf * 4 + m2 * 2 + (q >> 1);   // feat 8-f16-group 0..31
      const int gpw = (g8 & 16) | ((g8 ^ c) & 15);
#pragma unroll
      for (int n = 0; n < 4; ++n) {
        float v0 = fmaxf(fmaf(fmaf(acc[m2][n][0], rs[n], nmr[n]), gv.x, bev.x), 0.f);
        float v1 = fmaxf(fmaf(fmaf(acc[m2][n][1], rs[n], nmr[n]), gv.y, bev.y), 0.f);
        float v2 = fmaxf(fmaf(fmaf(acc[m2][n][2], rs[n], nmr[n]), gv.z, bev.z), 0.f);
        float v3 = fmaxf(fmaf(fmaf(acc[m2][n][3], rs[n], nmr[n]), gv.w, bev.w), 0.f);
        union { f16x4 v4; f16x2 v2[2]; } hh;
        hh.v2[0] = pk2(v0, v1); hh.v2[1] = pk2(v2, v3);
        *(f16x4*)(xbuf + (n * 16 + c) * 256 + gpw * 8 + j0) = hh.v4;
      }
    }
  }
  LGKMBAR();  // b4: x1 visible

  // ---------- GEMM2: K=256, chunks 4..11, ZERO barriers ----------
  f32x4 acc2[2][4];
#pragma unroll
  for (int m2 = 0; m2 < 2; ++m2)
#pragma unroll
    for (int n = 0; n < 4; ++n) acc2[m2][n] = (f32x4){0.f, 0.f, 0.f, 0.f};

#pragma unroll
  for (int j = 0; j < 8; ++j) {   // global chunk 4+j
    const int g = j * 4 + q;      // 0..31
    const int gp = (g & 16) | ((g ^ c) & 15);
    const f16_t* xr = xbuf + c * 256 + gp * 8;
    const f16x8 bf0 = *(const f16x8*)(xr);
    const f16x8 bf1 = *(const f16x8*)(xr + 16 * 256);
    const f16x8 bf2 = *(const f16x8*)(xr + 32 * 256);
    const f16x8 bf3 = *(const f16x8*)(xr + 48 * 256);
    const f16x8 a0 = afb[j & 1][0];
    const f16x8 a1 = afb[j & 1][1];
    if (j < 6) {  // reload ring slot with chunk 6+j
      afb[j & 1][0] = *(const f16x8*)(wp + ((6 + j) * 16 + wf * 2 + 0) * 512);
      afb[j & 1][1] = *(const f16x8*)(wp + ((6 + j) * 16 + wf * 2 + 1) * 512);
    }
    MFMA16(a0, bf0, acc2[0][0]);
    MFMA16(a0, bf1, acc2[0][1]);
    MFMA16(a0, bf2, acc2[0][2]);
    MFMA16(a0, bf3, acc2[0][3]);
    MFMA16(a1, bf0, acc2[1][0]);
    MFMA16(a1, bf1, acc2[1][1]);
    MFMA16(a1, bf2, acc2[1][2]);
    MFMA16(a1, bf3, acc2[1][3]);
  }

  // ---------- LN2 stats ----------
  {
    float s[4] = {0.f, 0.f, 0.f, 0.f}, sq[4] = {0.f, 0.f, 0.f, 0.f};
#pragma unroll
    for (int m2 = 0; m2 < 2; ++m2) {
      const float4 bv = *(const float4*)(b2 + featBase + m2 * 16 + q * 4);
#pragma unroll
      for (int r = 0; r < 4; ++r) {
        const float b = COMP(bv, r);
#pragma unroll
        for (int n = 0; n < 4; ++n) {
          float v = acc2[m2][n][r] + b;
          acc2[m2][n][r] = v;
          s[n] += v; sq[n] += v * v;
        }
      }
    }
#pragma unroll
    for (int n = 0; n < 4; ++n) {
      s[n] += __shfl_xor(s[n], 16, 64); s[n] += __shfl_xor(s[n], 32, 64);
      sq[n] += __shfl_xor(sq[n], 16, 64); sq[n] += __shfl_xor(sq[n], 32, 64);
    }
    if (q == 0) {
#pragma unroll
      for (int n = 0; n < 4; ++n) {
        ssum[wf * 64 + n * 16 + c] = s[n];
        ssq[wf * 64 + n * 16 + c] = sq[n];
      }
    }
  }
  LGKMBAR();  // b5

  if (t < 64) {
    float s = 0.f, sq = 0.f;
#pragma unroll
    for (int w = 0; w < 8; ++w) { s += ssum[w * 64 + t]; sq += ssq[w * 64 + t]; }
    float mu = s * (1.f / 256.f);
    float var = sq * (1.f / 256.f) - mu * mu;
    smean[t] = mu;
    srstd[t] = rsqrtf(var + 1e-5f);
  }
  LGKMBAR();  // b6

  // ---------- LN2 normalize + ReLU + dot(W3) + sigmoid ----------
  {
    float rs[4], nmr[4], p[4] = {0.f, 0.f, 0.f, 0.f};
#pragma unroll
    for (int n = 0; n < 4; ++n) {
      rs[n] = srstd[n * 16 + c];
      nmr[n] = -smean[n * 16 + c] * rs[n];
    }
#pragma unroll
    for (int m2 = 0; m2 < 2; ++m2) {
      const float4 gv = *(const float4*)(g2 + featBase + m2 * 16 + q * 4);
      const float4 bev = *(const float4*)(be2 + featBase + m2 * 16 + q * 4);
      const float4 wv = *(const float4*)(w3 + featBase + m2 * 16 + q * 4);
#pragma unroll
      for (int r = 0; r < 4; ++r) {
        const float gr = COMP(gv, r), ber = COMP(bev, r), wr = COMP(wv, r);
#pragma unroll
        for (int n = 0; n < 4; ++n) {
          float v = fmaxf(fmaf(fmaf(acc2[m2][n][r], rs[n], nmr[n]), gr, ber), 0.f);
          p[n] = fmaf(v, wr, p[n]);
        }
      }
    }
#pragma unroll
    for (int n = 0; n < 4; ++n) {
      p[n] += __shfl_xor(p[n], 16, 64); p[n] += __shfl_xor(p[n], 32, 64);
    }
    if (q == 0) {
#pragma unroll
      for (int n = 0; n < 4; ++n)
        ssum[wf * 64 + n * 16 + c] = p[n];   // ssum dead after b6 reduce
    }
  }
  LGKMBAR();  // b7
  if (t < 64) {
    int e = ebase + t;
    if (e < E) {
      float sres = b3[0];
#pragma unroll
      for (int w = 0; w < 8; ++w) sres += ssum[w * 64 + t];
      out[e] = 1.f / (1.f + __expf(-sres));
    }
  }
}

extern "C" void kernel_launch(void* const* d_in, const int* in_sizes, int n_in,
                              void* d_out, int out_size, void* d_ws, size_t ws_size,
                              hipStream_t stream) {
  const float* h = (const float*)d_in[0];
  const int* src = (const int*)d_in[1];
  const int* dst = (const int*)d_in[2];
  const float* W1 = (const float*)d_in[3];
  const float* b1 = (const float*)d_in[4];
  const float* g1 = (const float*)d_in[5];
  const float* be1 = (const float*)d_in[6];
  const float* W2 = (const float*)d_in[7];
  const float* b2 = (const float*)d_in[8];
  const float* g2 = (const float*)d_in[9];
  const float* be2 = (const float*)d_in[10];
  const float* W3 = (const float*)d_in[11];
  const float* b3 = (const float*)d_in[12];
  float* out = (float*)d_out;
  const int E = in_sizes[1];
  const int nrows = in_sizes[0] / 128;
  f16_t* wks = (f16_t*)d_ws;  // 98304 f16 = 196608 bytes

  wconv<<<256, 256, 0, stream>>>(W1, W2, wks);
  (void)hipFuncSetAttribute((const void*)fused_mlp,
                            hipFuncAttributeMaxDynamicSharedMemorySize, LDS_BYTES);
  const int tiles = (E + 63) / 64;
  fused_mlp<<<tiles, 512, LDS_BYTES, stream>>>(h, src, dst, wks, b1, g1, be1,
                                               b2, g2, be2, W3, b3, out, E, nrows);
}